// Round 8
// baseline (936.956 us; speedup 1.0000x reference)
//
#include <hip/hip_runtime.h>
#include <cstdint>
#include <cstddef>

// ---------------------------------------------------------------------------
// GateLoop block, round 13: sched_barrier(0) pins in the GEMM phase loop.
//   r12 was flat at 35% MfmaUtil. Model: if ds_reads execute AFTER the
//   pre-MFMA s_barrier, each phase serializes as [block-wide LDS burst,
//   matrix idle] -> [MFMA burst, LDS idle] = 36% predicted = 35% measured.
//   __builtin_amdgcn_s_barrier() is NOT a compiler fence: LLVM may sink
//   plain LDS loads (used only after the barrier) past it. P2/P4's asm
//   vmcnt ("memory") pins reads there; P1/P3 (the 8-read phases) have no
//   pin. Fix (rule-#18 family): sched_barrier(0) after {reads,stages}
//   (issue stays before s_barrier -> LDS service overlaps prior phase's
//   staggered MFMA drain) and after s_barrier (MFMA can't hoist above).
//   SINGLE change vs r12 -- clean A/B.
//   Carried: 256x256 tile, 8 waves 128x64 (acc 8x4), BK=64, 2 LDS dbuf,
//   balanced 8/4/8/4 phases, counted vmcnt(4) (never 0 mid-loop), chunk-XOR
//   swizzle (0 conflicts), XCD swizzle, fast gelu/sigmoid, consolidated
//   projections, vectorized pointwise kernels.
//
// Pipeline:
//   0. x -> fp16; weights -> transposed fp16 [N,K] (qkvg stacked)
//   1. mgemm x@[Wq|Wk|Wv|Wg] -> P[M,4096]; x@Wa -> ab (d_out)
//   2. a_transform in place (fp16, d_out)
//   3. chunked scan (3 passes, fp32 state); k*v inline;
//      pass3 writes y in-place over P's q columns
//   4. gn_gate + silu(g) (vectorized, in place on y cols of P)
//   5. mgemm y@Wo -> yo (d_out); ln1 -> x1 (xb slot)
//   6. mgemm x1@W1(+b1,fast gelu) -> h1 (overlays P); h1@W2(+b2) -> h2 (d_out)
//   7. ln2(x1 + h2) -> out (in place over h2)
//
// ws layout (MiB): 0 W1T(8) | 8 W2T(8) | 16 PWT(8) | 24 WoT(2) | 26 WaT(4) |
//   30 chunk(4) | 34 carry(2) | 36 stats | 37 xb(32) | 69 P(128) | 197 end.
// Aliases: ab & yo & h2 -> d_out; y over P q-cols; h1 -> P; x1 -> xb.
// ---------------------------------------------------------------------------

#define EPSN 1e-6f

typedef _Float16 f16;
typedef _Float16 f16x8 __attribute__((ext_vector_type(8)));
typedef _Float16 f16x4 __attribute__((ext_vector_type(4)));
typedef float    f32x4 __attribute__((ext_vector_type(4)));

static constexpr int    Bb     = 4;
static constexpr int    Ss     = 4096;
static constexpr int    Dd     = 1024;
static constexpr int    Ff     = 4096;
static constexpr int    Mrows  = Bb * Ss;                  // 16384
static constexpr size_t MD     = (size_t)Mrows * Dd;       // 16777216
static constexpr int    CHUNKS = 64;
static constexpr int    CLEN   = Ss / CHUNKS;              // 64
static constexpr int    BD     = Bb * Dd;                  // 4096
static constexpr int    CBD    = CHUNKS * BD;              // 262144
static constexpr size_t MiB    = 1024 * 1024;
static constexpr int    PLD    = 4096;                     // P row stride

__device__ __forceinline__ float fast_sigmoid(float x) {
    float e = __builtin_amdgcn_exp2f(-1.4426950408889634f * x);
    return __builtin_amdgcn_rcpf(1.0f + e);
}
__device__ __forceinline__ float gelu_tanh(float x) {
    float z = 0.7978845608028654f * (x + 0.044715f * x * x * x);
    z = fminf(fmaxf(z, -10.0f), 10.0f);          // tanh(+-10)=+-1 to fp32
    float e = __builtin_amdgcn_exp2f(2.885390081777927f * z);   // e^{2z}
    float t = (e - 1.0f) * __builtin_amdgcn_rcpf(e + 1.0f);
    return 0.5f * x * (1.0f + t);
}

// async global->LDS, 16 B per lane; lds dest = base + lane*16 (wave-uniform base)
__device__ __forceinline__ void async16(const void* g, void* l) {
    __builtin_amdgcn_global_load_lds(
        (const __attribute__((address_space(1))) unsigned int*)(uintptr_t)g,
        (__attribute__((address_space(3))) unsigned int*)(uintptr_t)l,
        16, 0, 0);
}

// ------- MFMA GEMM: C[M,N](ldc) = A[M,K](lda,f16) @ Bt[N,K](f16)^T ----------
// Tile 256x256, BK=64, 8 waves of 128x64 (acc 8x4), 2 LDS dbuf,
// 4 balanced phases/tile, counted vmcnt, sched-pinned issue order.
// EPI: 0 none | 1 bias+gelu | 2 bias
template <int EPI, typename TC>
__global__ __launch_bounds__(512, 2) void mgemm_k(const f16* __restrict__ A, int lda,
                                                  const f16* __restrict__ Bt,
                                                  TC* __restrict__ C, int ldc,
                                                  int M, int N, int K,
                                                  const float* __restrict__ bias) {
    // per buffer per matrix: [kk][256 rows][32 f16]  (32 KiB); 2 buffers
    __shared__ f16 sA[2 * 16384];
    __shared__ f16 sB[2 * 16384];
    const int tid  = threadIdx.x;
    const int wave = tid >> 6;        // 0..7
    const int lane = tid & 63;

    // XCD-chunked bijective swizzle (all grids have nwg % 8 == 0)
    const int gx  = gridDim.x;
    const int nwg = gx * gridDim.y;
    int bid = blockIdx.y * gx + blockIdx.x;
    bid = (bid & 7) * (nwg >> 3) + (bid >> 3);
    const int bm = (bid / gx) * 256;
    const int bn = (bid % gx) * 256;

    const int rw = (wave >> 2) * 128; // wave row offset (0 or 128)
    const int cw = (wave & 3) * 64;   // wave col offset (0..192)

    // staging: one gload = wave's 16 half-rows x 64 B of one k-half.
    // lane l -> row (l>>2), phys chunk (l&3); pre-swizzled global chunk
    // c_log = (l&3) ^ ((row>>1)&3) = (l&3) ^ ((l>>3)&3).
    const int swzcF = (((lane & 3) ^ (lane >> 3)) & 3) * 8;   // f16 units
    const f16* gA0 = A  + (size_t)(bm + wave * 16 + (lane >> 2)) * lda + swzcF;
    const f16* gB0 = Bt + (size_t)(bn + wave * 16 + (lane >> 2)) * K   + swzcF;

    f32x4 acc[8][4] = {};

    // fragment read: phys chunk = fk ^ ((fr>>1)&3); fr=lane&15, fk=lane>>4
    const int fr   = lane & 15;
    const int off0 = (((lane >> 4) ^ (lane >> 1)) & 3) * 8;   // f16 units

    const int NT = K >> 6;            // K-tiles of 64 (K 1024/4096)

// stage gload G (0/1 = rows 0-127/128-255) of k-half KK into buffer SB
#define STGA(SB, KOFF, KK, G)                                                  \
    async16(gA0 + (size_t)(G) * 128 * lda + (KOFF) + (KK) * 32,                \
            sA + (SB) * 16384 + (KK) * 8192 + ((G) * 128 + wave * 16) * 32)
#define STGB(SB, KOFF, KK, G)                                                  \
    async16(gB0 + (size_t)(G) * 128 * K + (KOFF) + (KK) * 32,                  \
            sB + (SB) * 16384 + (KK) * 8192 + ((G) * 128 + wave * 16) * 32)

#define LDA4(IH, KK, BUF)                                                      \
    _Pragma("unroll") for (int i = 0; i < 4; ++i)                              \
        a_[i] = *(const f16x8*)&sA[(BUF) * 16384 + (KK) * 8192 +               \
                                   (rw + ((IH) + i) * 16 + fr) * 32 + off0];
#define LDB4(KK, BUF)                                                          \
    _Pragma("unroll") for (int j = 0; j < 4; ++j)                              \
        b_[j] = *(const f16x8*)&sB[(BUF) * 16384 + (KK) * 8192 +               \
                                   (cw + j * 16 + fr) * 32 + off0];
#define MMQ(IH)                                                                \
    __builtin_amdgcn_s_setprio(1);                                             \
    _Pragma("unroll") for (int i = 0; i < 4; ++i)                              \
        _Pragma("unroll") for (int j = 0; j < 4; ++j)                          \
            acc[(IH) + i][j] = __builtin_amdgcn_mfma_f32_16x16x32_f16(         \
                a_[i], b_[j], acc[(IH) + i][j], 0, 0, 0);                      \
    __builtin_amdgcn_s_setprio(0);

// pinned phase boundary: {reads,stages} stay ABOVE the s_barrier (issue
// overlaps prior phase's MFMA drain); MFMA stays BELOW it.
#define PIN_BAR                                                                \
    __builtin_amdgcn_sched_barrier(0);                                         \
    __builtin_amdgcn_s_barrier();                                              \
    __builtin_amdgcn_sched_barrier(0);

    // prologue: stage tile 0 fully into buffer 0; drain; publish
    STGA(0, 0, 0, 0); STGA(0, 0, 0, 1); STGA(0, 0, 1, 0); STGA(0, 0, 1, 1);
    STGB(0, 0, 0, 0); STGB(0, 0, 0, 1); STGB(0, 0, 1, 0); STGB(0, 0, 1, 1);
    asm volatile("s_waitcnt vmcnt(0)" ::: "memory");
    __builtin_amdgcn_s_barrier();

    for (int t = 0; t < NT; ++t) {
        const int rd = t & 1, st = rd ^ 1;
        const int kS = (t + 1) * 64;
        const bool doSt = (t + 1) < NT;
        f16x8 a_[4], b_[4];

        // P1: A[0:4]k0 + B[0:4]k0 (8 reads); stage A-k0(t+1)
        LDB4(0, rd)
        LDA4(0, 0, rd)
        if (doSt) { STGA(st, kS, 0, 0); STGA(st, kS, 0, 1); }
        PIN_BAR
        MMQ(0)
        __builtin_amdgcn_s_barrier();

        // P2: A[4:8]k0 (4 reads); stage B-k0(t+1); counted wait
        // (drains A-k1(t)/B-k1(t) staged at t-1.P3/P4 -- needed by P3;
        //  leaves this tile's 4 newest in flight)
        LDA4(4, 0, rd)
        if (doSt) {
            STGB(st, kS, 0, 0); STGB(st, kS, 0, 1);
            asm volatile("s_waitcnt vmcnt(4)" ::: "memory");
        } else {
            asm volatile("s_waitcnt vmcnt(0)" ::: "memory");   // tail only
        }
        PIN_BAR
        MMQ(4)
        __builtin_amdgcn_s_barrier();

        // P3: A[0:4]k1 + B[0:4]k1 (8 reads); stage A-k1(t+1)
        LDB4(1, rd)
        LDA4(0, 1, rd)
        if (doSt) { STGA(st, kS, 1, 0); STGA(st, kS, 1, 1); }
        PIN_BAR
        MMQ(0)
        __builtin_amdgcn_s_barrier();

        // P4: A[4:8]k1 (4 reads); stage B-k1(t+1); counted wait
        // (drains A-k0(t+1)/B-k0(t+1) -- needed by t+1.P1)
        LDA4(4, 1, rd)
        if (doSt) {
            STGB(st, kS, 1, 0); STGB(st, kS, 1, 1);
            asm volatile("s_waitcnt vmcnt(4)" ::: "memory");
        }
        PIN_BAR
        MMQ(4)
        __builtin_amdgcn_s_barrier();
    }
#undef STGA
#undef STGB
#undef LDA4
#undef LDB4
#undef MMQ
#undef PIN_BAR

    // epilogue: C row = (lane>>4)*4 + reg, col = lane&15  (dtype-independent)
    const int er = (lane >> 4) * 4;
    const int ec = lane & 15;
#pragma unroll
    for (int i = 0; i < 8; ++i) {
#pragma unroll
        for (int j = 0; j < 4; ++j) {
            const int col = bn + cw + j * 16 + ec;
#pragma unroll
            for (int r = 0; r < 4; ++r) {
                const size_t row = (size_t)(bm + rw + i * 16 + er + r);
                float o = acc[i][j][r];
                if (EPI == 1 || EPI == 2) o += bias[col];
                if (EPI == 1) o = gelu_tanh(o);
                if (sizeof(TC) == 4) ((float*)C)[row * ldc + col] = o;
                else                 ((f16*)C)[row * ldc + col] = (f16)o;
            }
        }
    }
}

// ---------------- weight transpose+convert: Wt[n][k] = f16(W[k][n]) ---------
__global__ __launch_bounds__(256) void wtrans_k(const float* __restrict__ W,
                                                f16* __restrict__ Wt,
                                                int K, int N) {
    __shared__ float t[32][33];
    const int n0 = blockIdx.x * 32, k0 = blockIdx.y * 32;
    const int tx = threadIdx.x & 31, ty = threadIdx.x >> 5;   // 8 rows
#pragma unroll
    for (int i = 0; i < 32; i += 8)
        t[ty + i][tx] = W[(size_t)(k0 + ty + i) * N + n0 + tx];
    __syncthreads();
#pragma unroll
    for (int i = 0; i < 32; i += 8)
        Wt[(size_t)(n0 + ty + i) * K + k0 + tx] = (f16)t[tx][ty + i];
}

// ---------------- x fp32 -> fp16 --------------------------------------------
__global__ __launch_bounds__(256) void f2h_k(const float* __restrict__ x,
                                             f16* __restrict__ xh) {
    size_t i = ((size_t)blockIdx.x * 256 + threadIdx.x) * 4;
    float4 v = *(const float4*)&x[i];
    f16x4 s;
    s.x = (f16)v.x; s.y = (f16)v.y; s.z = (f16)v.z; s.w = (f16)v.w;
    *(f16x4*)&xh[i] = s;
}

// ------- a transform: a_c = sigmoid(|a|)*a/|a| (fp16 in place, x8) ----------
__global__ __launch_bounds__(256) void a_transform_k(f16* __restrict__ a2d) {
    size_t gid = (size_t)blockIdx.x * 256 + threadIdx.x;   // < M*D/8
    int    j8  = (int)(gid & 127) * 8;
    size_t row = gid >> 7;
    f16x8 vr = *(f16x8*)&a2d[row * 2048 + j8];
    f16x8 vi = *(f16x8*)&a2d[row * 2048 + 1024 + j8];
#pragma unroll
    for (int i = 0; i < 8; ++i) {
        float ar = (float)vr[i], ai = (float)vi[i];
        float mag = sqrtf(ar * ar + ai * ai);
        float sg  = fast_sigmoid(mag);
        float re, im;
        if (mag > 1e-30f) { float s = sg * __builtin_amdgcn_rcpf(mag); re = ar * s; im = ai * s; }
        else              { re = sg; im = 0.0f; }
        vr[i] = (f16)re; vi[i] = (f16)im;
    }
    *(f16x8*)&a2d[row * 2048 + j8]        = vr;
    *(f16x8*)&a2d[row * 2048 + 1024 + j8] = vi;
}

// ---------------- chunked complex scan (fp32 state) -------------------------
// P columns: q 0..1023 | k 1024..2047 | v 2048..3071 | g 3072..4095
__global__ __launch_bounds__(256) void scan_pass1_k(const f16* __restrict__ a2d,
                                                    const f16* __restrict__ P,
                                                    float4* __restrict__ chunk) {
    int tid = blockIdx.x * 256 + threadIdx.x;    // < CBD
    int d   = tid & 1023;
    int t1  = tid >> 10;
    int b   = t1 & 3;
    int c   = t1 >> 2;
    int t0  = c * CLEN;
    int rbase = b * Ss;
    float Are = 1.0f, Aim = 0.0f, Hre = 0.0f, Him = 0.0f;
    for (int t = t0; t < t0 + CLEN; ++t) {
        int r = rbase + t;
        float are = (float)a2d[(size_t)r * 2048 + d];
        float aim = (float)a2d[(size_t)r * 2048 + 1024 + d];
        float kvv = (float)P[(size_t)r * PLD + 1024 + d]
                  * (float)P[(size_t)r * PLD + 2048 + d];
        float hre = are * Hre - aim * Him + kvv;
        float him = are * Him + aim * Hre;
        Hre = hre; Him = him;
        float pre = are * Are - aim * Aim;
        float pim = are * Aim + aim * Are;
        Are = pre; Aim = pim;
    }
    chunk[tid] = make_float4(Are, Aim, Hre, Him);
}

__global__ __launch_bounds__(256) void scan_pass2_k(const float4* __restrict__ chunk,
                                                    float2* __restrict__ carry,
                                                    float* __restrict__ stats) {
    int tid = blockIdx.x * blockDim.x + threadIdx.x;  // < B*D = 4096
    if (tid < 512) stats[tid] = 0.0f;                 // ws is poisoned: zero gn stats
    float hre = 0.0f, him = 0.0f;
    for (int c = 0; c < CHUNKS; ++c) {
        int task = c * BD + tid;
        float4 ch = chunk[task];
        carry[task] = make_float2(hre, him);
        float nre = ch.x * hre - ch.y * him + ch.z;
        float nim = ch.x * him + ch.y * hre + ch.w;
        hre = nre; him = nim;
    }
}

// pass3: y written in place over P's q columns (per-elem read-then-write)
__global__ __launch_bounds__(256) void scan_pass3_k(const f16* __restrict__ a2d,
                                                    f16* __restrict__ P,
                                                    const float2* __restrict__ carry,
                                                    float* __restrict__ stats) {
    int tid = blockIdx.x * 256 + threadIdx.x;    // < CBD
    int d   = tid & 1023;
    int t1  = tid >> 10;
    int b   = t1 & 3;
    int c   = t1 >> 2;
    int t0  = c * CLEN;
    int rbase = b * Ss;
    float2 cr = carry[tid];
    float hre = cr.x, him = cr.y;
    float sre = 0.0f, sim = 0.0f, s2 = 0.0f;
    for (int t = t0; t < t0 + CLEN; ++t) {
        int r = rbase + t;
        float are = (float)a2d[(size_t)r * 2048 + d];
        float aim = (float)a2d[(size_t)r * 2048 + 1024 + d];
        float kvv = (float)P[(size_t)r * PLD + 1024 + d]
                  * (float)P[(size_t)r * PLD + 2048 + d];
        float nre = are * hre - aim * him + kvv;
        float nim = are * him + aim * hre;
        hre = nre; him = nim;
        float qv  = (float)P[(size_t)r * PLD + d];
        float yr_ = qv * hre;
        float yi_ = qv * him;
        P[(size_t)r * PLD + d] = (f16)yr_;       // overwrite q with y (safe)
        sre += yr_; sim += yi_; s2 += yr_ * yr_ + yi_ * yi_;
    }
#pragma unroll
    for (int off = 16; off > 0; off >>= 1) {
        sre += __shfl_down(sre, off, 32);
        sim += __shfl_down(sim, off, 32);
        s2  += __shfl_down(s2,  off, 32);
    }
    if ((threadIdx.x & 31) == 0) {
        int idx = (b * 32 + (d >> 5)) * 4;
        atomicAdd(&stats[idx + 0], sre);
        atomicAdd(&stats[idx + 1], sim);
        atomicAdd(&stats[idx + 2], s2);
    }
}

// ------- groupnorm (real) + silu(g)-gate, f16x8, in place on y cols ---------
__global__ __launch_bounds__(256) void gn_gate_k(f16* __restrict__ P,
                                                 const float* __restrict__ stats,
                                                 const float* __restrict__ gn_scale,
                                                 const float* __restrict__ gn_bias) {
    size_t gid = (size_t)blockIdx.x * 256 + threadIdx.x;  // < M*D/8
    int d8  = (int)(gid & 127) * 8;
    int row = (int)(gid >> 7);
    int b   = row >> 12;
    int grp = d8 >> 5;
    const float* st = &stats[(b * 32 + grp) * 4];
    const float invN = 1.0f / 131072.0f;       // S * (D/G)
    float mre = st[0] * invN;
    float mim = st[1] * invN;
    float var = st[2] * invN - mre * mre - mim * mim;
    float rstd = rsqrtf(var + EPSN);
    f16x8 yv = *(f16x8*)&P[(size_t)row * PLD + d8];
    f16x8 gv = *(const f16x8*)&P[(size_t)row * PLD + 3072 + d8];
#pragma unroll
    for (int i = 0; i < 8; ++i) {
        float re = ((float)yv[i] - mre) * rstd * gn_scale[d8 + i] + gn_bias[d8 + i];
        float gx = (float)gv[i];
        yv[i] = (f16)(re * gx * fast_sigmoid(gx));
    }
    *(f16x8*)&P[(size_t)row * PLD + d8] = yv;
}

// ---------------- layernorm over D=1024: out = LN(a + b) --------------------
__device__ __forceinline__ float ldf(const float* p, size_t i) { return p[i]; }
__device__ __forceinline__ float ldf(const f16* p, size_t i)   { return (float)p[i]; }
__device__ __forceinline__ void  stf(float* p, size_t i, float v) { p[i] = v; }
__device__ __forceinline__ void  stf(f16* p, size_t i, float v)   { p[i] = (f16)v; }

__device__ __forceinline__ float block_reduce_sum(float v, float* s4, int tid) {
#pragma unroll
    for (int off = 32; off > 0; off >>= 1) v += __shfl_down(v, off, 64);
    __syncthreads();
    if ((tid & 63) == 0) s4[tid >> 6] = v;
    __syncthreads();
    return s4[0] + s4[1] + s4[2] + s4[3];
}

template <typename TA, typename TB, typename TO>
__global__ __launch_bounds__(256) void ln_k(const TA* __restrict__ a,
                                            const TB* __restrict__ b,
                                            const float* __restrict__ scale,
                                            const float* __restrict__ bias,
                                            TO* __restrict__ out) {
    __shared__ float s4[4];
    int row = blockIdx.x;
    size_t base = (size_t)row * 1024;
    int tid = threadIdx.x;
    float v[4];
    float s = 0.0f;
#pragma unroll
    for (int i = 0; i < 4; ++i) {
        int d = tid + i * 256;
        v[i] = ldf(a, base + d) + ldf(b, base + d);
        s += v[i];
    }
    float mu = block_reduce_sum(s, s4, tid) * (1.0f / 1024.0f);
    float s2 = 0.0f;
#pragma unroll
    for (int i = 0; i < 4; ++i) {
        float dv = v[i] - mu;
        s2 += dv * dv;
    }
    float var = block_reduce_sum(s2, s4, tid) * (1.0f / 1024.0f);
    float rstd = rsqrtf(var + EPSN);
#pragma unroll
    for (int i = 0; i < 4; ++i) {
        int d = tid + i * 256;
        stf(out, base + d, (v[i] - mu) * rstd * scale[d] + bias[d]);
    }
}

// ---------------------------------------------------------------------------
extern "C" void kernel_launch(void* const* d_in, const int* in_sizes, int n_in,
                              void* d_out, int out_size, void* d_ws, size_t ws_size,
                              hipStream_t stream) {
    const float* x        = (const float*)d_in[0];
    const float* Wq       = (const float*)d_in[1];
    const float* Wk       = (const float*)d_in[2];
    const float* Wv       = (const float*)d_in[3];
    const float* Wa       = (const float*)d_in[4];
    const float* Wg       = (const float*)d_in[5];
    const float* Wo       = (const float*)d_in[6];
    const float* gn_scale = (const float*)d_in[7];
    const float* gn_bias  = (const float*)d_in[8];
    const float* ln1_s    = (const float*)d_in[9];
    const float* ln1_b    = (const float*)d_in[10];
    const float* W1       = (const float*)d_in[11];
    const float* b1       = (const float*)d_in[12];
    const float* W2       = (const float*)d_in[13];
    const float* b2       = (const float*)d_in[14];
    const float* ln2_s    = (const float*)d_in[15];
    const float* ln2_b    = (const float*)d_in[16];
    float* out = (float*)d_out;

    char* base = (char*)d_ws;
    f16* W1T = (f16*)(base + 0 * MiB);    // [4096, 1024]
    f16* W2T = (f16*)(base + 8 * MiB);    // [1024, 4096]
    f16* PWT = (f16*)(base + 16 * MiB);   // [4096, 1024] = [Wq|Wk|Wv|Wg]^T
    f16* WoT = (f16*)(base + 24 * MiB);   // [1024, 1024]
    f16* WaT = (f16*)(base + 26 * MiB);   // [2048, 1024]
    float4* chunk = (float4*)(base + 30 * MiB);
    float2* carry = (float2*)(base + 34 * MiB);
    float*  stats = (float*)(base + 36 * MiB);
    f16* xb  = (f16*)(base + 37 * MiB);   // [M,1024] fp16 = 32 MiB
    f16* P   = (f16*)(base + 69 * MiB);   // [M,4096] fp16 = 128 MiB, ends 197
    // aliases (lifetimes verified):
    f16*   ab = (f16*)d_out;              // [M,2048] fp16 = 64 MiB; dead after pass3
    f16*   yo = (f16*)d_out;              // Wo out [M,1024] f16; a dead by then
    f16*   x1 = xb;                       // post-ln1; xb dead after projections
    f16*   h1 = P;                        // [M,F] f16 = 128 MiB; P dead after Wo
    float* h2 = (float*)d_out;            // fp32 [M,D]; yo dead after ln1

    dim3 blk(256);
    dim3 gblk(512);

    // 0. conversions (PWT rows: 0 q | 1024 k | 2048 v | 3072 g)
    f2h_k<<<Mrows, blk, 0, stream>>>(x, xb);
    wtrans_k<<<dim3(128, 32), blk, 0, stream>>>(W1, W1T, Dd, Ff);
    wtrans_k<<<dim3(32, 128), blk, 0, stream>>>(W2, W2T, Ff, Dd);
    wtrans_k<<<dim3(32, 32),  blk, 0, stream>>>(Wq, PWT + 0u * 1048576, Dd, Dd);
    wtrans_k<<<dim3(32, 32),  blk, 0, stream>>>(Wk, PWT + 1u * 1048576, Dd, Dd);
    wtrans_k<<<dim3(32, 32),  blk, 0, stream>>>(Wv, PWT + 2u * 1048576, Dd, Dd);
    wtrans_k<<<dim3(32, 32),  blk, 0, stream>>>(Wg, PWT + 3u * 1048576, Dd, Dd);
    wtrans_k<<<dim3(32, 32),  blk, 0, stream>>>(Wo, WoT, Dd, Dd);
    wtrans_k<<<dim3(64, 32),  blk, 0, stream>>>(Wa, WaT, Dd, 2 * Dd);

    // 1. projections: one N=4096 GEMM (q|k|v|g) + one N=2048 (a)
    mgemm_k<0, f16><<<dim3(16, 64), gblk, 0, stream>>>(xb, Dd, PWT, P, PLD, Mrows, 4096, Dd, nullptr);
    mgemm_k<0, f16><<<dim3(8, 64),  gblk, 0, stream>>>(xb, Dd, WaT, ab, 2048, Mrows, 2048, Dd, nullptr);

    // 2. a transform (fp16, in place in d_out)
    a_transform_k<<<MD / (256 * 8), blk, 0, stream>>>(ab);

    // 3. chunked scan (k*v inline; y in-place over q cols of P)
    scan_pass1_k<<<CBD / 256, blk, 0, stream>>>(ab, P, chunk);
    scan_pass2_k<<<BD / 256, blk, 0, stream>>>(chunk, carry, stats);
    scan_pass3_k<<<CBD / 256, blk, 0, stream>>>(ab, P, carry, stats);

    // 4. groupnorm + silu(g) gate (in place on y cols of P)
    gn_gate_k<<<MD / (256 * 8), blk, 0, stream>>>(P, stats, gn_scale, gn_bias);

    // 5. output projection (A = y cols of P, lda=PLD) + ln1
    mgemm_k<0, f16><<<dim3(4, 64), gblk, 0, stream>>>(P, PLD, WoT, yo, Dd, Mrows, Dd, Dd, nullptr);
    ln_k<float, f16, f16><<<Mrows, blk, 0, stream>>>(x, yo, ln1_s, ln1_b, x1);

    // 6. MLP (h1 overlays P; h2 -> d_out fp32)
    mgemm_k<1, f16  ><<<dim3(16, 64), gblk, 0, stream>>>(x1, Dd, W1T, h1, Ff, Mrows, Ff, Dd, b1);
    mgemm_k<2, float><<<dim3(4, 64),  gblk, 0, stream>>>(h1, Ff, W2T, h2, Dd, Mrows, Dd, Ff, b2);

    // 7. final layernorm -> out (in place over h2: per-thread read-then-write)
    ln_k<f16, float, float><<<Mrows, blk, 0, stream>>>(x1, h2, ln2_s, ln2_b, out);
}

// Round 9
// 936.636 us; speedup vs baseline: 1.0003x; 1.0003x over previous
//
#include <hip/hip_runtime.h>
#include <cstdint>
#include <cstddef>

// ---------------------------------------------------------------------------
// GateLoop block, round 14: non-GEMM pass overhaul; GEMM = r12 exact.
//   r13 post-mortem: sched_barrier pins flat on W1, regressed others ->
//   reverted. Three schedule rounds all plateau at ~35% MfmaUtil; pivot to
//   the orthogonal ~237us of non-GEMM time (ideal ~140):
//   (a) a_transform kernel DELETED: pass1/pass3 apply sigmoid(|a|)*a/|a|
//       inline in f32 on raw a (removes a 128MiB RW pass AND one f16
//       rounding; both passes compute bit-identical a -> scan algebra
//       consistent).
//   (b) scans vectorized x4 (f16x4 = 8B/lane sweet spot, G13): 4 adjacent
//       d-columns per thread = 4 independent recurrence chains (ILP),
//       1/4 the instructions, 512B/wave loads. Stats reduce = width-8
//       shuffle (8 threads per 32-col group, alignment checked).
//   Carried GEMM (r12): 256x256 tile, 8 waves 128x64 (acc 8x4), BK=64,
//   2 LDS dbuf, balanced 8/4/8/4 phases, counted vmcnt(4), chunk-XOR
//   swizzle (0 conflicts), XCD swizzle, fast gelu/sigmoid.
//
// Pipeline:
//   0. x -> fp16; weights -> transposed fp16 [N,K] (qkvg stacked)
//   1. mgemm x@[Wq|Wk|Wv|Wg] -> P[M,4096]; x@Wa -> ab (d_out, raw)
//   2. chunked scan (3 passes, fp32 state); a-transform + k*v inline;
//      pass3 writes y in-place over P's q columns
//   3. gn_gate + silu(g) (vectorized, in place on y cols of P)
//   4. mgemm y@Wo -> yo (d_out); ln1 -> x1 (xb slot)
//   5. mgemm x1@W1(+b1,fast gelu) -> h1 (overlays P); h1@W2(+b2) -> h2 (d_out)
//   6. ln2(x1 + h2) -> out (in place over h2)
//
// ws layout (MiB): 0 W1T(8) | 8 W2T(8) | 16 PWT(8) | 24 WoT(2) | 26 WaT(4) |
//   30 chunk(4) | 34 carry(2) | 36 stats | 37 xb(32) | 69 P(128) | 197 end.
// Aliases: ab & yo & h2 -> d_out; y over P q-cols; h1 -> P; x1 -> xb.
// ---------------------------------------------------------------------------

#define EPSN 1e-6f

typedef _Float16 f16;
typedef _Float16 f16x8 __attribute__((ext_vector_type(8)));
typedef _Float16 f16x4 __attribute__((ext_vector_type(4)));
typedef float    f32x4 __attribute__((ext_vector_type(4)));

static constexpr int    Bb     = 4;
static constexpr int    Ss     = 4096;
static constexpr int    Dd     = 1024;
static constexpr int    Ff     = 4096;
static constexpr int    Mrows  = Bb * Ss;                  // 16384
static constexpr size_t MD     = (size_t)Mrows * Dd;       // 16777216
static constexpr int    CHUNKS = 64;
static constexpr int    CLEN   = Ss / CHUNKS;              // 64
static constexpr int    BD     = Bb * Dd;                  // 4096
static constexpr int    CBD    = CHUNKS * BD;              // 262144
static constexpr size_t MiB    = 1024 * 1024;
static constexpr int    PLD    = 4096;                     // P row stride

__device__ __forceinline__ float fast_sigmoid(float x) {
    float e = __builtin_amdgcn_exp2f(-1.4426950408889634f * x);
    return __builtin_amdgcn_rcpf(1.0f + e);
}
__device__ __forceinline__ float gelu_tanh(float x) {
    float z = 0.7978845608028654f * (x + 0.044715f * x * x * x);
    z = fminf(fmaxf(z, -10.0f), 10.0f);          // tanh(+-10)=+-1 to fp32
    float e = __builtin_amdgcn_exp2f(2.885390081777927f * z);   // e^{2z}
    float t = (e - 1.0f) * __builtin_amdgcn_rcpf(e + 1.0f);
    return 0.5f * x * (1.0f + t);
}
// a-transform, inline: (are,aim) = sigmoid(|a|) * a / |a|  (f32, unrounded)
__device__ __forceinline__ void a_xform(float ar, float ai, float& re, float& im) {
    float mag = sqrtf(ar * ar + ai * ai);
    float sg  = fast_sigmoid(mag);
    if (mag > 1e-30f) {
        float s = sg * __builtin_amdgcn_rcpf(mag);
        re = ar * s; im = ai * s;
    } else { re = sg; im = 0.0f; }
}

// async global->LDS, 16 B per lane; lds dest = base + lane*16 (wave-uniform base)
__device__ __forceinline__ void async16(const void* g, void* l) {
    __builtin_amdgcn_global_load_lds(
        (const __attribute__((address_space(1))) unsigned int*)(uintptr_t)g,
        (__attribute__((address_space(3))) unsigned int*)(uintptr_t)l,
        16, 0, 0);
}

// ------- MFMA GEMM: C[M,N](ldc) = A[M,K](lda,f16) @ Bt[N,K](f16)^T ----------
// r12 exact: Tile 256x256, BK=64, 8 waves of 128x64 (acc 8x4), 2 LDS dbuf,
// 4 balanced phases/tile, counted vmcnt. EPI: 0 none | 1 bias+gelu | 2 bias
template <int EPI, typename TC>
__global__ __launch_bounds__(512, 2) void mgemm_k(const f16* __restrict__ A, int lda,
                                                  const f16* __restrict__ Bt,
                                                  TC* __restrict__ C, int ldc,
                                                  int M, int N, int K,
                                                  const float* __restrict__ bias) {
    // per buffer per matrix: [kk][256 rows][32 f16]  (32 KiB); 2 buffers
    __shared__ f16 sA[2 * 16384];
    __shared__ f16 sB[2 * 16384];
    const int tid  = threadIdx.x;
    const int wave = tid >> 6;        // 0..7
    const int lane = tid & 63;

    // XCD-chunked bijective swizzle (all grids have nwg % 8 == 0)
    const int gx  = gridDim.x;
    const int nwg = gx * gridDim.y;
    int bid = blockIdx.y * gx + blockIdx.x;
    bid = (bid & 7) * (nwg >> 3) + (bid >> 3);
    const int bm = (bid / gx) * 256;
    const int bn = (bid % gx) * 256;

    const int rw = (wave >> 2) * 128; // wave row offset (0 or 128)
    const int cw = (wave & 3) * 64;   // wave col offset (0..192)

    // staging: one gload = wave's 16 half-rows x 64 B of one k-half.
    // lane l -> row (l>>2), phys chunk (l&3); pre-swizzled global chunk
    // c_log = (l&3) ^ ((row>>1)&3) = (l&3) ^ ((l>>3)&3).
    const int swzcF = (((lane & 3) ^ (lane >> 3)) & 3) * 8;   // f16 units
    const f16* gA0 = A  + (size_t)(bm + wave * 16 + (lane >> 2)) * lda + swzcF;
    const f16* gB0 = Bt + (size_t)(bn + wave * 16 + (lane >> 2)) * K   + swzcF;

    f32x4 acc[8][4] = {};

    // fragment read: phys chunk = fk ^ ((fr>>1)&3); fr=lane&15, fk=lane>>4
    const int fr   = lane & 15;
    const int off0 = (((lane >> 4) ^ (lane >> 1)) & 3) * 8;   // f16 units

    const int NT = K >> 6;            // K-tiles of 64 (K 1024/4096)

// stage gload G (0/1 = rows 0-127/128-255) of k-half KK into buffer SB
#define STGA(SB, KOFF, KK, G)                                                  \
    async16(gA0 + (size_t)(G) * 128 * lda + (KOFF) + (KK) * 32,                \
            sA + (SB) * 16384 + (KK) * 8192 + ((G) * 128 + wave * 16) * 32)
#define STGB(SB, KOFF, KK, G)                                                  \
    async16(gB0 + (size_t)(G) * 128 * K + (KOFF) + (KK) * 32,                  \
            sB + (SB) * 16384 + (KK) * 8192 + ((G) * 128 + wave * 16) * 32)

#define LDA4(IH, KK, BUF)                                                      \
    _Pragma("unroll") for (int i = 0; i < 4; ++i)                              \
        a_[i] = *(const f16x8*)&sA[(BUF) * 16384 + (KK) * 8192 +               \
                                   (rw + ((IH) + i) * 16 + fr) * 32 + off0];
#define LDB4(KK, BUF)                                                          \
    _Pragma("unroll") for (int j = 0; j < 4; ++j)                              \
        b_[j] = *(const f16x8*)&sB[(BUF) * 16384 + (KK) * 8192 +               \
                                   (cw + j * 16 + fr) * 32 + off0];
#define MMQ(IH)                                                                \
    __builtin_amdgcn_s_setprio(1);                                             \
    _Pragma("unroll") for (int i = 0; i < 4; ++i)                              \
        _Pragma("unroll") for (int j = 0; j < 4; ++j)                          \
            acc[(IH) + i][j] = __builtin_amdgcn_mfma_f32_16x16x32_f16(         \
                a_[i], b_[j], acc[(IH) + i][j], 0, 0, 0);                      \
    __builtin_amdgcn_s_setprio(0);

    // prologue: stage tile 0 fully into buffer 0; drain; publish
    STGA(0, 0, 0, 0); STGA(0, 0, 0, 1); STGA(0, 0, 1, 0); STGA(0, 0, 1, 1);
    STGB(0, 0, 0, 0); STGB(0, 0, 0, 1); STGB(0, 0, 1, 0); STGB(0, 0, 1, 1);
    asm volatile("s_waitcnt vmcnt(0)" ::: "memory");
    __builtin_amdgcn_s_barrier();

    for (int t = 0; t < NT; ++t) {
        const int rd = t & 1, st = rd ^ 1;
        const int kS = (t + 1) * 64;
        const bool doSt = (t + 1) < NT;
        f16x8 a_[4], b_[4];

        // P1: A[0:4]k0 + B[0:4]k0 (8 reads); stage A-k0(t+1)
        LDB4(0, rd)
        LDA4(0, 0, rd)
        if (doSt) { STGA(st, kS, 0, 0); STGA(st, kS, 0, 1); }
        __builtin_amdgcn_s_barrier();
        MMQ(0)
        __builtin_amdgcn_s_barrier();

        // P2: A[4:8]k0 (4 reads); stage B-k0(t+1); counted wait
        LDA4(4, 0, rd)
        if (doSt) {
            STGB(st, kS, 0, 0); STGB(st, kS, 0, 1);
            asm volatile("s_waitcnt vmcnt(4)" ::: "memory");
        } else {
            asm volatile("s_waitcnt vmcnt(0)" ::: "memory");   // tail only
        }
        __builtin_amdgcn_s_barrier();
        MMQ(4)
        __builtin_amdgcn_s_barrier();

        // P3: A[0:4]k1 + B[0:4]k1 (8 reads); stage A-k1(t+1)
        LDB4(1, rd)
        LDA4(0, 1, rd)
        if (doSt) { STGA(st, kS, 1, 0); STGA(st, kS, 1, 1); }
        __builtin_amdgcn_s_barrier();
        MMQ(0)
        __builtin_amdgcn_s_barrier();

        // P4: A[4:8]k1 (4 reads); stage B-k1(t+1); counted wait
        LDA4(4, 1, rd)
        if (doSt) {
            STGB(st, kS, 1, 0); STGB(st, kS, 1, 1);
            asm volatile("s_waitcnt vmcnt(4)" ::: "memory");
        }
        __builtin_amdgcn_s_barrier();
        MMQ(4)
        __builtin_amdgcn_s_barrier();
    }
#undef STGA
#undef STGB
#undef LDA4
#undef LDB4
#undef MMQ

    // epilogue: C row = (lane>>4)*4 + reg, col = lane&15  (dtype-independent)
    const int er = (lane >> 4) * 4;
    const int ec = lane & 15;
#pragma unroll
    for (int i = 0; i < 8; ++i) {
#pragma unroll
        for (int j = 0; j < 4; ++j) {
            const int col = bn + cw + j * 16 + ec;
#pragma unroll
            for (int r = 0; r < 4; ++r) {
                const size_t row = (size_t)(bm + rw + i * 16 + er + r);
                float o = acc[i][j][r];
                if (EPI == 1 || EPI == 2) o += bias[col];
                if (EPI == 1) o = gelu_tanh(o);
                if (sizeof(TC) == 4) ((float*)C)[row * ldc + col] = o;
                else                 ((f16*)C)[row * ldc + col] = (f16)o;
            }
        }
    }
}

// ---------------- weight transpose+convert: Wt[n][k] = f16(W[k][n]) ---------
__global__ __launch_bounds__(256) void wtrans_k(const float* __restrict__ W,
                                                f16* __restrict__ Wt,
                                                int K, int N) {
    __shared__ float t[32][33];
    const int n0 = blockIdx.x * 32, k0 = blockIdx.y * 32;
    const int tx = threadIdx.x & 31, ty = threadIdx.x >> 5;   // 8 rows
#pragma unroll
    for (int i = 0; i < 32; i += 8)
        t[ty + i][tx] = W[(size_t)(k0 + ty + i) * N + n0 + tx];
    __syncthreads();
#pragma unroll
    for (int i = 0; i < 32; i += 8)
        Wt[(size_t)(n0 + ty + i) * K + k0 + tx] = (f16)t[tx][ty + i];
}

// ---------------- x fp32 -> fp16 --------------------------------------------
__global__ __launch_bounds__(256) void f2h_k(const float* __restrict__ x,
                                             f16* __restrict__ xh) {
    size_t i = ((size_t)blockIdx.x * 256 + threadIdx.x) * 4;
    float4 v = *(const float4*)&x[i];
    f16x4 s;
    s.x = (f16)v.x; s.y = (f16)v.y; s.z = (f16)v.z; s.w = (f16)v.w;
    *(f16x4*)&xh[i] = s;
}

// ---------------- chunked complex scan (fp32 state, x4 vectorized) ----------
// P columns: q 0..1023 | k 1024..2047 | v 2048..3071 | g 3072..4095
// a2d holds RAW a-projection [M,2048]; transform applied inline (a_xform).
__global__ __launch_bounds__(256) void scan_pass1_k(const f16* __restrict__ a2d,
                                                    const f16* __restrict__ P,
                                                    float4* __restrict__ chunk) {
    int tid = blockIdx.x * 256 + threadIdx.x;    // < CBD/4
    int d   = (tid & 255) * 4;
    int t1  = tid >> 8;
    int b   = t1 & 3;
    int c   = t1 >> 2;
    int t0  = c * CLEN;
    int rbase = b * Ss;
    float Are[4], Aim[4], Hre[4], Him[4];
#pragma unroll
    for (int u = 0; u < 4; ++u) { Are[u] = 1.0f; Aim[u] = 0.0f; Hre[u] = 0.0f; Him[u] = 0.0f; }
    for (int t = t0; t < t0 + CLEN; ++t) {
        size_t r = (size_t)(rbase + t);
        f16x4 arv = *(const f16x4*)&a2d[r * 2048 + d];
        f16x4 aiv = *(const f16x4*)&a2d[r * 2048 + 1024 + d];
        f16x4 kv_ = *(const f16x4*)&P[r * PLD + 1024 + d];
        f16x4 vv_ = *(const f16x4*)&P[r * PLD + 2048 + d];
#pragma unroll
        for (int u = 0; u < 4; ++u) {
            float are, aim;
            a_xform((float)arv[u], (float)aiv[u], are, aim);
            float kvv = (float)kv_[u] * (float)vv_[u];
            float hre = are * Hre[u] - aim * Him[u] + kvv;
            float him = are * Him[u] + aim * Hre[u];
            Hre[u] = hre; Him[u] = him;
            float pre = are * Are[u] - aim * Aim[u];
            float pim = are * Aim[u] + aim * Are[u];
            Are[u] = pre; Aim[u] = pim;
        }
    }
#pragma unroll
    for (int u = 0; u < 4; ++u)
        chunk[(size_t)t1 * 1024 + d + u] = make_float4(Are[u], Aim[u], Hre[u], Him[u]);
}

__global__ __launch_bounds__(256) void scan_pass2_k(const float4* __restrict__ chunk,
                                                    float2* __restrict__ carry,
                                                    float* __restrict__ stats) {
    int tid = blockIdx.x * blockDim.x + threadIdx.x;  // < B*D = 4096
    if (tid < 512) stats[tid] = 0.0f;                 // ws is poisoned: zero gn stats
    float hre = 0.0f, him = 0.0f;
    for (int c = 0; c < CHUNKS; ++c) {
        int task = c * BD + tid;
        float4 ch = chunk[task];
        carry[task] = make_float2(hre, him);
        float nre = ch.x * hre - ch.y * him + ch.z;
        float nim = ch.x * him + ch.y * hre + ch.w;
        hre = nre; him = nim;
    }
}

// pass3: y written in place over P's q columns (per-elem read-then-write)
__global__ __launch_bounds__(256) void scan_pass3_k(const f16* __restrict__ a2d,
                                                    f16* __restrict__ P,
                                                    const float2* __restrict__ carry,
                                                    float* __restrict__ stats) {
    int tid = blockIdx.x * 256 + threadIdx.x;    // < CBD/4
    int d   = (tid & 255) * 4;
    int t1  = tid >> 8;
    int b   = t1 & 3;
    int c   = t1 >> 2;
    int t0  = c * CLEN;
    int rbase = b * Ss;
    float hre[4], him[4];
#pragma unroll
    for (int u = 0; u < 4; ++u) {
        float2 cr = carry[(size_t)t1 * 1024 + d + u];
        hre[u] = cr.x; him[u] = cr.y;
    }
    float sre = 0.0f, sim = 0.0f, s2 = 0.0f;
    for (int t = t0; t < t0 + CLEN; ++t) {
        size_t r = (size_t)(rbase + t);
        f16x4 arv = *(const f16x4*)&a2d[r * 2048 + d];
        f16x4 aiv = *(const f16x4*)&a2d[r * 2048 + 1024 + d];
        f16x4 kv_ = *(const f16x4*)&P[r * PLD + 1024 + d];
        f16x4 vv_ = *(const f16x4*)&P[r * PLD + 2048 + d];
        f16x4 qv_ = *(const f16x4*)&P[r * PLD + d];
        f16x4 yv;
#pragma unroll
        for (int u = 0; u < 4; ++u) {
            float are, aim;
            a_xform((float)arv[u], (float)aiv[u], are, aim);
            float kvv = (float)kv_[u] * (float)vv_[u];
            float nre = are * hre[u] - aim * him[u] + kvv;
            float nim = are * him[u] + aim * hre[u];
            hre[u] = nre; him[u] = nim;
            float qv  = (float)qv_[u];
            float yr_ = qv * nre;
            float yi_ = qv * nim;
            yv[u] = (f16)yr_;
            sre += yr_; sim += yi_; s2 += yr_ * yr_ + yi_ * yi_;
        }
        *(f16x4*)&P[r * PLD + d] = yv;           // overwrite q with y (safe)
    }
    // 8 threads per 32-col group (d = (tid&255)*4; group = (tid&255)>>3)
#pragma unroll
    for (int off = 4; off > 0; off >>= 1) {
        sre += __shfl_down(sre, off, 8);
        sim += __shfl_down(sim, off, 8);
        s2  += __shfl_down(s2,  off, 8);
    }
    if ((threadIdx.x & 7) == 0) {
        int idx = (b * 32 + (d >> 5)) * 4;
        atomicAdd(&stats[idx + 0], sre);
        atomicAdd(&stats[idx + 1], sim);
        atomicAdd(&stats[idx + 2], s2);
    }
}

// ------- groupnorm (real) + silu(g)-gate, f16x8, in place on y cols ---------
__global__ __launch_bounds__(256) void gn_gate_k(f16* __restrict__ P,
                                                 const float* __restrict__ stats,
                                                 const float* __restrict__ gn_scale,
                                                 const float* __restrict__ gn_bias) {
    size_t gid = (size_t)blockIdx.x * 256 + threadIdx.x;  // < M*D/8
    int d8  = (int)(gid & 127) * 8;
    int row = (int)(gid >> 7);
    int b   = row >> 12;
    int grp = d8 >> 5;
    const float* st = &stats[(b * 32 + grp) * 4];
    const float invN = 1.0f / 131072.0f;       // S * (D/G)
    float mre = st[0] * invN;
    float mim = st[1] * invN;
    float var = st[2] * invN - mre * mre - mim * mim;
    float rstd = rsqrtf(var + EPSN);
    f16x8 yv = *(f16x8*)&P[(size_t)row * PLD + d8];
    f16x8 gv = *(const f16x8*)&P[(size_t)row * PLD + 3072 + d8];
#pragma unroll
    for (int i = 0; i < 8; ++i) {
        float re = ((float)yv[i] - mre) * rstd * gn_scale[d8 + i] + gn_bias[d8 + i];
        float gx = (float)gv[i];
        yv[i] = (f16)(re * gx * fast_sigmoid(gx));
    }
    *(f16x8*)&P[(size_t)row * PLD + d8] = yv;
}

// ---------------- layernorm over D=1024: out = LN(a + b) --------------------
__device__ __forceinline__ float ldf(const float* p, size_t i) { return p[i]; }
__device__ __forceinline__ float ldf(const f16* p, size_t i)   { return (float)p[i]; }
__device__ __forceinline__ void  stf(float* p, size_t i, float v) { p[i] = v; }
__device__ __forceinline__ void  stf(f16* p, size_t i, float v)   { p[i] = (f16)v; }

__device__ __forceinline__ float block_reduce_sum(float v, float* s4, int tid) {
#pragma unroll
    for (int off = 32; off > 0; off >>= 1) v += __shfl_down(v, off, 64);
    __syncthreads();
    if ((tid & 63) == 0) s4[tid >> 6] = v;
    __syncthreads();
    return s4[0] + s4[1] + s4[2] + s4[3];
}

template <typename TA, typename TB, typename TO>
__global__ __launch_bounds__(256) void ln_k(const TA* __restrict__ a,
                                            const TB* __restrict__ b,
                                            const float* __restrict__ scale,
                                            const float* __restrict__ bias,
                                            TO* __restrict__ out) {
    __shared__ float s4[4];
    int row = blockIdx.x;
    size_t base = (size_t)row * 1024;
    int tid = threadIdx.x;
    float v[4];
    float s = 0.0f;
#pragma unroll
    for (int i = 0; i < 4; ++i) {
        int d = tid + i * 256;
        v[i] = ldf(a, base + d) + ldf(b, base + d);
        s += v[i];
    }
    float mu = block_reduce_sum(s, s4, tid) * (1.0f / 1024.0f);
    float s2 = 0.0f;
#pragma unroll
    for (int i = 0; i < 4; ++i) {
        float dv = v[i] - mu;
        s2 += dv * dv;
    }
    float var = block_reduce_sum(s2, s4, tid) * (1.0f / 1024.0f);
    float rstd = rsqrtf(var + EPSN);
#pragma unroll
    for (int i = 0; i < 4; ++i) {
        int d = tid + i * 256;
        stf(out, base + d, (v[i] - mu) * rstd * scale[d] + bias[d]);
    }
}

// ---------------------------------------------------------------------------
extern "C" void kernel_launch(void* const* d_in, const int* in_sizes, int n_in,
                              void* d_out, int out_size, void* d_ws, size_t ws_size,
                              hipStream_t stream) {
    const float* x        = (const float*)d_in[0];
    const float* Wq       = (const float*)d_in[1];
    const float* Wk       = (const float*)d_in[2];
    const float* Wv       = (const float*)d_in[3];
    const float* Wa       = (const float*)d_in[4];
    const float* Wg       = (const float*)d_in[5];
    const float* Wo       = (const float*)d_in[6];
    const float* gn_scale = (const float*)d_in[7];
    const float* gn_bias  = (const float*)d_in[8];
    const float* ln1_s    = (const float*)d_in[9];
    const float* ln1_b    = (const float*)d_in[10];
    const float* W1       = (const float*)d_in[11];
    const float* b1       = (const float*)d_in[12];
    const float* W2       = (const float*)d_in[13];
    const float* b2       = (const float*)d_in[14];
    const float* ln2_s    = (const float*)d_in[15];
    const float* ln2_b    = (const float*)d_in[16];
    float* out = (float*)d_out;

    char* base = (char*)d_ws;
    f16* W1T = (f16*)(base + 0 * MiB);    // [4096, 1024]
    f16* W2T = (f16*)(base + 8 * MiB);    // [1024, 4096]
    f16* PWT = (f16*)(base + 16 * MiB);   // [4096, 1024] = [Wq|Wk|Wv|Wg]^T
    f16* WoT = (f16*)(base + 24 * MiB);   // [1024, 1024]
    f16* WaT = (f16*)(base + 26 * MiB);   // [2048, 1024]
    float4* chunk = (float4*)(base + 30 * MiB);
    float2* carry = (float2*)(base + 34 * MiB);
    float*  stats = (float*)(base + 36 * MiB);
    f16* xb  = (f16*)(base + 37 * MiB);   // [M,1024] fp16 = 32 MiB
    f16* P   = (f16*)(base + 69 * MiB);   // [M,4096] fp16 = 128 MiB, ends 197
    // aliases (lifetimes verified):
    f16*   ab = (f16*)d_out;              // [M,2048] raw a, f16 = 64 MiB; dead after pass3
    f16*   yo = (f16*)d_out;              // Wo out [M,1024] f16; a dead by then
    f16*   x1 = xb;                       // post-ln1; xb dead after projections
    f16*   h1 = P;                        // [M,F] f16 = 128 MiB; P dead after Wo
    float* h2 = (float*)d_out;            // fp32 [M,D]; yo dead after ln1

    dim3 blk(256);
    dim3 gblk(512);

    // 0. conversions (PWT rows: 0 q | 1024 k | 2048 v | 3072 g)
    f2h_k<<<Mrows, blk, 0, stream>>>(x, xb);
    wtrans_k<<<dim3(128, 32), blk, 0, stream>>>(W1, W1T, Dd, Ff);
    wtrans_k<<<dim3(32, 128), blk, 0, stream>>>(W2, W2T, Ff, Dd);
    wtrans_k<<<dim3(32, 32),  blk, 0, stream>>>(Wq, PWT + 0u * 1048576, Dd, Dd);
    wtrans_k<<<dim3(32, 32),  blk, 0, stream>>>(Wk, PWT + 1u * 1048576, Dd, Dd);
    wtrans_k<<<dim3(32, 32),  blk, 0, stream>>>(Wv, PWT + 2u * 1048576, Dd, Dd);
    wtrans_k<<<dim3(32, 32),  blk, 0, stream>>>(Wg, PWT + 3u * 1048576, Dd, Dd);
    wtrans_k<<<dim3(32, 32),  blk, 0, stream>>>(Wo, WoT, Dd, Dd);
    wtrans_k<<<dim3(64, 32),  blk, 0, stream>>>(Wa, WaT, Dd, 2 * Dd);

    // 1. projections: one N=4096 GEMM (q|k|v|g) + one N=2048 (a, raw)
    mgemm_k<0, f16><<<dim3(16, 64), gblk, 0, stream>>>(xb, Dd, PWT, P, PLD, Mrows, 4096, Dd, nullptr);
    mgemm_k<0, f16><<<dim3(8, 64),  gblk, 0, stream>>>(xb, Dd, WaT, ab, 2048, Mrows, 2048, Dd, nullptr);

    // 2. chunked scan (a-transform + k*v inline; y in-place over q cols of P)
    scan_pass1_k<<<CBD / (256 * 4), blk, 0, stream>>>(ab, P, chunk);
    scan_pass2_k<<<BD / 256, blk, 0, stream>>>(chunk, carry, stats);
    scan_pass3_k<<<CBD / (256 * 4), blk, 0, stream>>>(ab, P, carry, stats);

    // 3. groupnorm + silu(g) gate (in place on y cols of P)
    gn_gate_k<<<MD / (256 * 8), blk, 0, stream>>>(P, stats, gn_scale, gn_bias);

    // 4. output projection (A = y cols of P, lda=PLD) + ln1
    mgemm_k<0, f16><<<dim3(4, 64), gblk, 0, stream>>>(P, PLD, WoT, yo, Dd, Mrows, Dd, Dd, nullptr);
    ln_k<float, f16, f16><<<Mrows, blk, 0, stream>>>(x, yo, ln1_s, ln1_b, x1);

    // 5. MLP (h1 overlays P; h2 -> d_out fp32)
    mgemm_k<1, f16  ><<<dim3(16, 64), gblk, 0, stream>>>(x1, Dd, W1T, h1, Ff, Mrows, Ff, Dd, b1);
    mgemm_k<2, float><<<dim3(4, 64),  gblk, 0, stream>>>(h1, Ff, W2T, h2, Dd, Mrows, Dd, Ff, b2);

    // 6. final layernorm -> out (in place over h2: per-thread read-then-write)
    ln_k<f16, float, float><<<Mrows, blk, 0, stream>>>(x1, h2, ln2_s, ln2_b, out);
}

// Round 10
// 890.332 us; speedup vs baseline: 1.0524x; 1.0520x over previous
//
#include <hip/hip_runtime.h>
#include <cstdint>
#include <cstddef>

// ---------------------------------------------------------------------------
// GateLoop block, round 15: scalar scans + inline a-transform; GEMM = r12.
//   r14 post-mortem: x4-vectorized scans cut scan occupancy 16->4 waves/CU
//   (grid 1024->256 blocks). The scan is a LATENCY-bound dependent loop --
//   TLP was its latency hiding; ILP chains don't help the serial recurrence.
//   Net +65us regression vs r12 scans. r15 reverts to r12's scalar scan
//   structure (1 col/thread, 16 waves/CU) but KEEPS the good half of r14:
//   a_transform kernel deleted, sigmoid(|a|)*a/|a| applied inline in f32
//   in pass1/pass3 (removes a 128MiB RW pass + one f16 rounding; both
//   passes compute identical a -> scan algebra consistent; ~4us extra VALU).
//   GEMM unchanged from r12 (proven 892-class): 256x256 tile, 8 waves
//   128x64 (acc 8x4), BK=64, 2 LDS dbuf, balanced 8/4/8/4 phases, counted
//   vmcnt(4) (never 0 mid-loop), chunk-XOR swizzle (0 conflicts), XCD
//   swizzle, fast gelu/sigmoid, consolidated projections.
//
// Pipeline:
//   0. x -> fp16; weights -> transposed fp16 [N,K] (qkvg stacked)
//   1. mgemm x@[Wq|Wk|Wv|Wg] -> P[M,4096]; x@Wa -> ab (d_out, raw)
//   2. chunked scan (3 passes, fp32 state); a-transform + k*v inline;
//      pass3 writes y in-place over P's q columns
//   3. gn_gate + silu(g) (vectorized, in place on y cols of P)
//   4. mgemm y@Wo -> yo (d_out); ln1 -> x1 (xb slot)
//   5. mgemm x1@W1(+b1,fast gelu) -> h1 (overlays P); h1@W2(+b2) -> h2 (d_out)
//   6. ln2(x1 + h2) -> out (in place over h2)
//
// ws layout (MiB): 0 W1T(8) | 8 W2T(8) | 16 PWT(8) | 24 WoT(2) | 26 WaT(4) |
//   30 chunk(4) | 34 carry(2) | 36 stats | 37 xb(32) | 69 P(128) | 197 end.
// Aliases: ab & yo & h2 -> d_out; y over P q-cols; h1 -> P; x1 -> xb.
// ---------------------------------------------------------------------------

#define EPSN 1e-6f

typedef _Float16 f16;
typedef _Float16 f16x8 __attribute__((ext_vector_type(8)));
typedef _Float16 f16x4 __attribute__((ext_vector_type(4)));
typedef float    f32x4 __attribute__((ext_vector_type(4)));

static constexpr int    Bb     = 4;
static constexpr int    Ss     = 4096;
static constexpr int    Dd     = 1024;
static constexpr int    Ff     = 4096;
static constexpr int    Mrows  = Bb * Ss;                  // 16384
static constexpr size_t MD     = (size_t)Mrows * Dd;       // 16777216
static constexpr int    CHUNKS = 64;
static constexpr int    CLEN   = Ss / CHUNKS;              // 64
static constexpr int    BD     = Bb * Dd;                  // 4096
static constexpr int    CBD    = CHUNKS * BD;              // 262144
static constexpr size_t MiB    = 1024 * 1024;
static constexpr int    PLD    = 4096;                     // P row stride

__device__ __forceinline__ float fast_sigmoid(float x) {
    float e = __builtin_amdgcn_exp2f(-1.4426950408889634f * x);
    return __builtin_amdgcn_rcpf(1.0f + e);
}
__device__ __forceinline__ float gelu_tanh(float x) {
    float z = 0.7978845608028654f * (x + 0.044715f * x * x * x);
    z = fminf(fmaxf(z, -10.0f), 10.0f);          // tanh(+-10)=+-1 to fp32
    float e = __builtin_amdgcn_exp2f(2.885390081777927f * z);   // e^{2z}
    float t = (e - 1.0f) * __builtin_amdgcn_rcpf(e + 1.0f);
    return 0.5f * x * (1.0f + t);
}
// a-transform, inline: (are,aim) = sigmoid(|a|) * a / |a|  (f32, unrounded)
__device__ __forceinline__ void a_xform(float ar, float ai, float& re, float& im) {
    float mag = sqrtf(ar * ar + ai * ai);
    float sg  = fast_sigmoid(mag);
    if (mag > 1e-30f) {
        float s = sg * __builtin_amdgcn_rcpf(mag);
        re = ar * s; im = ai * s;
    } else { re = sg; im = 0.0f; }
}

// async global->LDS, 16 B per lane; lds dest = base + lane*16 (wave-uniform base)
__device__ __forceinline__ void async16(const void* g, void* l) {
    __builtin_amdgcn_global_load_lds(
        (const __attribute__((address_space(1))) unsigned int*)(uintptr_t)g,
        (__attribute__((address_space(3))) unsigned int*)(uintptr_t)l,
        16, 0, 0);
}

// ------- MFMA GEMM: C[M,N](ldc) = A[M,K](lda,f16) @ Bt[N,K](f16)^T ----------
// r12 exact: Tile 256x256, BK=64, 8 waves of 128x64 (acc 8x4), 2 LDS dbuf,
// 4 balanced phases/tile, counted vmcnt. EPI: 0 none | 1 bias+gelu | 2 bias
template <int EPI, typename TC>
__global__ __launch_bounds__(512, 2) void mgemm_k(const f16* __restrict__ A, int lda,
                                                  const f16* __restrict__ Bt,
                                                  TC* __restrict__ C, int ldc,
                                                  int M, int N, int K,
                                                  const float* __restrict__ bias) {
    // per buffer per matrix: [kk][256 rows][32 f16]  (32 KiB); 2 buffers
    __shared__ f16 sA[2 * 16384];
    __shared__ f16 sB[2 * 16384];
    const int tid  = threadIdx.x;
    const int wave = tid >> 6;        // 0..7
    const int lane = tid & 63;

    // XCD-chunked bijective swizzle (all grids have nwg % 8 == 0)
    const int gx  = gridDim.x;
    const int nwg = gx * gridDim.y;
    int bid = blockIdx.y * gx + blockIdx.x;
    bid = (bid & 7) * (nwg >> 3) + (bid >> 3);
    const int bm = (bid / gx) * 256;
    const int bn = (bid % gx) * 256;

    const int rw = (wave >> 2) * 128; // wave row offset (0 or 128)
    const int cw = (wave & 3) * 64;   // wave col offset (0..192)

    // staging: one gload = wave's 16 half-rows x 64 B of one k-half.
    // lane l -> row (l>>2), phys chunk (l&3); pre-swizzled global chunk
    // c_log = (l&3) ^ ((row>>1)&3) = (l&3) ^ ((l>>3)&3).
    const int swzcF = (((lane & 3) ^ (lane >> 3)) & 3) * 8;   // f16 units
    const f16* gA0 = A  + (size_t)(bm + wave * 16 + (lane >> 2)) * lda + swzcF;
    const f16* gB0 = Bt + (size_t)(bn + wave * 16 + (lane >> 2)) * K   + swzcF;

    f32x4 acc[8][4] = {};

    // fragment read: phys chunk = fk ^ ((fr>>1)&3); fr=lane&15, fk=lane>>4
    const int fr   = lane & 15;
    const int off0 = (((lane >> 4) ^ (lane >> 1)) & 3) * 8;   // f16 units

    const int NT = K >> 6;            // K-tiles of 64 (K 1024/4096)

// stage gload G (0/1 = rows 0-127/128-255) of k-half KK into buffer SB
#define STGA(SB, KOFF, KK, G)                                                  \
    async16(gA0 + (size_t)(G) * 128 * lda + (KOFF) + (KK) * 32,                \
            sA + (SB) * 16384 + (KK) * 8192 + ((G) * 128 + wave * 16) * 32)
#define STGB(SB, KOFF, KK, G)                                                  \
    async16(gB0 + (size_t)(G) * 128 * K + (KOFF) + (KK) * 32,                  \
            sB + (SB) * 16384 + (KK) * 8192 + ((G) * 128 + wave * 16) * 32)

#define LDA4(IH, KK, BUF)                                                      \
    _Pragma("unroll") for (int i = 0; i < 4; ++i)                              \
        a_[i] = *(const f16x8*)&sA[(BUF) * 16384 + (KK) * 8192 +               \
                                   (rw + ((IH) + i) * 16 + fr) * 32 + off0];
#define LDB4(KK, BUF)                                                          \
    _Pragma("unroll") for (int j = 0; j < 4; ++j)                              \
        b_[j] = *(const f16x8*)&sB[(BUF) * 16384 + (KK) * 8192 +               \
                                   (cw + j * 16 + fr) * 32 + off0];
#define MMQ(IH)                                                                \
    __builtin_amdgcn_s_setprio(1);                                             \
    _Pragma("unroll") for (int i = 0; i < 4; ++i)                              \
        _Pragma("unroll") for (int j = 0; j < 4; ++j)                          \
            acc[(IH) + i][j] = __builtin_amdgcn_mfma_f32_16x16x32_f16(         \
                a_[i], b_[j], acc[(IH) + i][j], 0, 0, 0);                      \
    __builtin_amdgcn_s_setprio(0);

    // prologue: stage tile 0 fully into buffer 0; drain; publish
    STGA(0, 0, 0, 0); STGA(0, 0, 0, 1); STGA(0, 0, 1, 0); STGA(0, 0, 1, 1);
    STGB(0, 0, 0, 0); STGB(0, 0, 0, 1); STGB(0, 0, 1, 0); STGB(0, 0, 1, 1);
    asm volatile("s_waitcnt vmcnt(0)" ::: "memory");
    __builtin_amdgcn_s_barrier();

    for (int t = 0; t < NT; ++t) {
        const int rd = t & 1, st = rd ^ 1;
        const int kS = (t + 1) * 64;
        const bool doSt = (t + 1) < NT;
        f16x8 a_[4], b_[4];

        // P1: A[0:4]k0 + B[0:4]k0 (8 reads); stage A-k0(t+1)
        LDB4(0, rd)
        LDA4(0, 0, rd)
        if (doSt) { STGA(st, kS, 0, 0); STGA(st, kS, 0, 1); }
        __builtin_amdgcn_s_barrier();
        MMQ(0)
        __builtin_amdgcn_s_barrier();

        // P2: A[4:8]k0 (4 reads); stage B-k0(t+1); counted wait
        LDA4(4, 0, rd)
        if (doSt) {
            STGB(st, kS, 0, 0); STGB(st, kS, 0, 1);
            asm volatile("s_waitcnt vmcnt(4)" ::: "memory");
        } else {
            asm volatile("s_waitcnt vmcnt(0)" ::: "memory");   // tail only
        }
        __builtin_amdgcn_s_barrier();
        MMQ(4)
        __builtin_amdgcn_s_barrier();

        // P3: A[0:4]k1 + B[0:4]k1 (8 reads); stage A-k1(t+1)
        LDB4(1, rd)
        LDA4(0, 1, rd)
        if (doSt) { STGA(st, kS, 1, 0); STGA(st, kS, 1, 1); }
        __builtin_amdgcn_s_barrier();
        MMQ(0)
        __builtin_amdgcn_s_barrier();

        // P4: A[4:8]k1 (4 reads); stage B-k1(t+1); counted wait
        LDA4(4, 1, rd)
        if (doSt) {
            STGB(st, kS, 1, 0); STGB(st, kS, 1, 1);
            asm volatile("s_waitcnt vmcnt(4)" ::: "memory");
        }
        __builtin_amdgcn_s_barrier();
        MMQ(4)
        __builtin_amdgcn_s_barrier();
    }
#undef STGA
#undef STGB
#undef LDA4
#undef LDB4
#undef MMQ

    // epilogue: C row = (lane>>4)*4 + reg, col = lane&15  (dtype-independent)
    const int er = (lane >> 4) * 4;
    const int ec = lane & 15;
#pragma unroll
    for (int i = 0; i < 8; ++i) {
#pragma unroll
        for (int j = 0; j < 4; ++j) {
            const int col = bn + cw + j * 16 + ec;
#pragma unroll
            for (int r = 0; r < 4; ++r) {
                const size_t row = (size_t)(bm + rw + i * 16 + er + r);
                float o = acc[i][j][r];
                if (EPI == 1 || EPI == 2) o += bias[col];
                if (EPI == 1) o = gelu_tanh(o);
                if (sizeof(TC) == 4) ((float*)C)[row * ldc + col] = o;
                else                 ((f16*)C)[row * ldc + col] = (f16)o;
            }
        }
    }
}

// ---------------- weight transpose+convert: Wt[n][k] = f16(W[k][n]) ---------
__global__ __launch_bounds__(256) void wtrans_k(const float* __restrict__ W,
                                                f16* __restrict__ Wt,
                                                int K, int N) {
    __shared__ float t[32][33];
    const int n0 = blockIdx.x * 32, k0 = blockIdx.y * 32;
    const int tx = threadIdx.x & 31, ty = threadIdx.x >> 5;   // 8 rows
#pragma unroll
    for (int i = 0; i < 32; i += 8)
        t[ty + i][tx] = W[(size_t)(k0 + ty + i) * N + n0 + tx];
    __syncthreads();
#pragma unroll
    for (int i = 0; i < 32; i += 8)
        Wt[(size_t)(n0 + ty + i) * K + k0 + tx] = (f16)t[tx][ty + i];
}

// ---------------- x fp32 -> fp16 --------------------------------------------
__global__ __launch_bounds__(256) void f2h_k(const float* __restrict__ x,
                                             f16* __restrict__ xh) {
    size_t i = ((size_t)blockIdx.x * 256 + threadIdx.x) * 4;
    float4 v = *(const float4*)&x[i];
    f16x4 s;
    s.x = (f16)v.x; s.y = (f16)v.y; s.z = (f16)v.z; s.w = (f16)v.w;
    *(f16x4*)&xh[i] = s;
}

// ---------------- chunked complex scan (fp32 state, scalar cols) ------------
// P columns: q 0..1023 | k 1024..2047 | v 2048..3071 | g 3072..4095
// a2d holds RAW a-projection [M,2048]; transform applied inline (a_xform).
__global__ __launch_bounds__(256) void scan_pass1_k(const f16* __restrict__ a2d,
                                                    const f16* __restrict__ P,
                                                    float4* __restrict__ chunk) {
    int tid = blockIdx.x * 256 + threadIdx.x;    // < CBD
    int d   = tid & 1023;
    int t1  = tid >> 10;
    int b   = t1 & 3;
    int c   = t1 >> 2;
    int t0  = c * CLEN;
    int rbase = b * Ss;
    float Are = 1.0f, Aim = 0.0f, Hre = 0.0f, Him = 0.0f;
    for (int t = t0; t < t0 + CLEN; ++t) {
        size_t r = (size_t)(rbase + t);
        float are, aim;
        a_xform((float)a2d[r * 2048 + d], (float)a2d[r * 2048 + 1024 + d], are, aim);
        float kvv = (float)P[r * PLD + 1024 + d]
                  * (float)P[r * PLD + 2048 + d];
        float hre = are * Hre - aim * Him + kvv;
        float him = are * Him + aim * Hre;
        Hre = hre; Him = him;
        float pre = are * Are - aim * Aim;
        float pim = are * Aim + aim * Are;
        Are = pre; Aim = pim;
    }
    chunk[tid] = make_float4(Are, Aim, Hre, Him);
}

__global__ __launch_bounds__(256) void scan_pass2_k(const float4* __restrict__ chunk,
                                                    float2* __restrict__ carry,
                                                    float* __restrict__ stats) {
    int tid = blockIdx.x * blockDim.x + threadIdx.x;  // < B*D = 4096
    if (tid < 512) stats[tid] = 0.0f;                 // ws is poisoned: zero gn stats
    float hre = 0.0f, him = 0.0f;
    for (int c = 0; c < CHUNKS; ++c) {
        int task = c * BD + tid;
        float4 ch = chunk[task];
        carry[task] = make_float2(hre, him);
        float nre = ch.x * hre - ch.y * him + ch.z;
        float nim = ch.x * him + ch.y * hre + ch.w;
        hre = nre; him = nim;
    }
}

// pass3: y written in place over P's q columns (per-elem read-then-write)
__global__ __launch_bounds__(256) void scan_pass3_k(const f16* __restrict__ a2d,
                                                    f16* __restrict__ P,
                                                    const float2* __restrict__ carry,
                                                    float* __restrict__ stats) {
    int tid = blockIdx.x * 256 + threadIdx.x;    // < CBD
    int d   = tid & 1023;
    int t1  = tid >> 10;
    int b   = t1 & 3;
    int c   = t1 >> 2;
    int t0  = c * CLEN;
    int rbase = b * Ss;
    float2 cr = carry[tid];
    float hre = cr.x, him = cr.y;
    float sre = 0.0f, sim = 0.0f, s2 = 0.0f;
    for (int t = t0; t < t0 + CLEN; ++t) {
        size_t r = (size_t)(rbase + t);
        float are, aim;
        a_xform((float)a2d[r * 2048 + d], (float)a2d[r * 2048 + 1024 + d], are, aim);
        float kvv = (float)P[r * PLD + 1024 + d]
                  * (float)P[r * PLD + 2048 + d];
        float nre = are * hre - aim * him + kvv;
        float nim = are * him + aim * hre;
        hre = nre; him = nim;
        float qv  = (float)P[r * PLD + d];
        float yr_ = qv * hre;
        float yi_ = qv * him;
        P[r * PLD + d] = (f16)yr_;               // overwrite q with y (safe)
        sre += yr_; sim += yi_; s2 += yr_ * yr_ + yi_ * yi_;
    }
#pragma unroll
    for (int off = 16; off > 0; off >>= 1) {
        sre += __shfl_down(sre, off, 32);
        sim += __shfl_down(sim, off, 32);
        s2  += __shfl_down(s2,  off, 32);
    }
    if ((threadIdx.x & 31) == 0) {
        int idx = (b * 32 + (d >> 5)) * 4;
        atomicAdd(&stats[idx + 0], sre);
        atomicAdd(&stats[idx + 1], sim);
        atomicAdd(&stats[idx + 2], s2);
    }
}

// ------- groupnorm (real) + silu(g)-gate, f16x8, in place on y cols ---------
__global__ __launch_bounds__(256) void gn_gate_k(f16* __restrict__ P,
                                                 const float* __restrict__ stats,
                                                 const float* __restrict__ gn_scale,
                                                 const float* __restrict__ gn_bias) {
    size_t gid = (size_t)blockIdx.x * 256 + threadIdx.x;  // < M*D/8
    int d8  = (int)(gid & 127) * 8;
    int row = (int)(gid >> 7);
    int b   = row >> 12;
    int grp = d8 >> 5;
    const float* st = &stats[(b * 32 + grp) * 4];
    const float invN = 1.0f / 131072.0f;       // S * (D/G)
    float mre = st[0] * invN;
    float mim = st[1] * invN;
    float var = st[2] * invN - mre * mre - mim * mim;
    float rstd = rsqrtf(var + EPSN);
    f16x8 yv = *(f16x8*)&P[(size_t)row * PLD + d8];
    f16x8 gv = *(const f16x8*)&P[(size_t)row * PLD + 3072 + d8];
#pragma unroll
    for (int i = 0; i < 8; ++i) {
        float re = ((float)yv[i] - mre) * rstd * gn_scale[d8 + i] + gn_bias[d8 + i];
        float gx = (float)gv[i];
        yv[i] = (f16)(re * gx * fast_sigmoid(gx));
    }
    *(f16x8*)&P[(size_t)row * PLD + d8] = yv;
}

// ---------------- layernorm over D=1024: out = LN(a + b) --------------------
__device__ __forceinline__ float ldf(const float* p, size_t i) { return p[i]; }
__device__ __forceinline__ float ldf(const f16* p, size_t i)   { return (float)p[i]; }
__device__ __forceinline__ void  stf(float* p, size_t i, float v) { p[i] = v; }
__device__ __forceinline__ void  stf(f16* p, size_t i, float v)   { p[i] = (f16)v; }

__device__ __forceinline__ float block_reduce_sum(float v, float* s4, int tid) {
#pragma unroll
    for (int off = 32; off > 0; off >>= 1) v += __shfl_down(v, off, 64);
    __syncthreads();
    if ((tid & 63) == 0) s4[tid >> 6] = v;
    __syncthreads();
    return s4[0] + s4[1] + s4[2] + s4[3];
}

template <typename TA, typename TB, typename TO>
__global__ __launch_bounds__(256) void ln_k(const TA* __restrict__ a,
                                            const TB* __restrict__ b,
                                            const float* __restrict__ scale,
                                            const float* __restrict__ bias,
                                            TO* __restrict__ out) {
    __shared__ float s4[4];
    int row = blockIdx.x;
    size_t base = (size_t)row * 1024;
    int tid = threadIdx.x;
    float v[4];
    float s = 0.0f;
#pragma unroll
    for (int i = 0; i < 4; ++i) {
        int d = tid + i * 256;
        v[i] = ldf(a, base + d) + ldf(b, base + d);
        s += v[i];
    }
    float mu = block_reduce_sum(s, s4, tid) * (1.0f / 1024.0f);
    float s2 = 0.0f;
#pragma unroll
    for (int i = 0; i < 4; ++i) {
        float dv = v[i] - mu;
        s2 += dv * dv;
    }
    float var = block_reduce_sum(s2, s4, tid) * (1.0f / 1024.0f);
    float rstd = rsqrtf(var + EPSN);
#pragma unroll
    for (int i = 0; i < 4; ++i) {
        int d = tid + i * 256;
        stf(out, base + d, (v[i] - mu) * rstd * scale[d] + bias[d]);
    }
}

// ---------------------------------------------------------------------------
extern "C" void kernel_launch(void* const* d_in, const int* in_sizes, int n_in,
                              void* d_out, int out_size, void* d_ws, size_t ws_size,
                              hipStream_t stream) {
    const float* x        = (const float*)d_in[0];
    const float* Wq       = (const float*)d_in[1];
    const float* Wk       = (const float*)d_in[2];
    const float* Wv       = (const float*)d_in[3];
    const float* Wa       = (const float*)d_in[4];
    const float* Wg       = (const float*)d_in[5];
    const float* Wo       = (const float*)d_in[6];
    const float* gn_scale = (const float*)d_in[7];
    const float* gn_bias  = (const float*)d_in[8];
    const float* ln1_s    = (const float*)d_in[9];
    const float* ln1_b    = (const float*)d_in[10];
    const float* W1       = (const float*)d_in[11];
    const float* b1       = (const float*)d_in[12];
    const float* W2       = (const float*)d_in[13];
    const float* b2       = (const float*)d_in[14];
    const float* ln2_s    = (const float*)d_in[15];
    const float* ln2_b    = (const float*)d_in[16];
    float* out = (float*)d_out;

    char* base = (char*)d_ws;
    f16* W1T = (f16*)(base + 0 * MiB);    // [4096, 1024]
    f16* W2T = (f16*)(base + 8 * MiB);    // [1024, 4096]
    f16* PWT = (f16*)(base + 16 * MiB);   // [4096, 1024] = [Wq|Wk|Wv|Wg]^T
    f16* WoT = (f16*)(base + 24 * MiB);   // [1024, 1024]
    f16* WaT = (f16*)(base + 26 * MiB);   // [2048, 1024]
    float4* chunk = (float4*)(base + 30 * MiB);
    float2* carry = (float2*)(base + 34 * MiB);
    float*  stats = (float*)(base + 36 * MiB);
    f16* xb  = (f16*)(base + 37 * MiB);   // [M,1024] fp16 = 32 MiB
    f16* P   = (f16*)(base + 69 * MiB);   // [M,4096] fp16 = 128 MiB, ends 197
    // aliases (lifetimes verified):
    f16*   ab = (f16*)d_out;              // [M,2048] raw a, f16 = 64 MiB; dead after pass3
    f16*   yo = (f16*)d_out;              // Wo out [M,1024] f16; a dead by then
    f16*   x1 = xb;                       // post-ln1; xb dead after projections
    f16*   h1 = P;                        // [M,F] f16 = 128 MiB; P dead after Wo
    float* h2 = (float*)d_out;            // fp32 [M,D]; yo dead after ln1

    dim3 blk(256);
    dim3 gblk(512);

    // 0. conversions (PWT rows: 0 q | 1024 k | 2048 v | 3072 g)
    f2h_k<<<Mrows, blk, 0, stream>>>(x, xb);
    wtrans_k<<<dim3(128, 32), blk, 0, stream>>>(W1, W1T, Dd, Ff);
    wtrans_k<<<dim3(32, 128), blk, 0, stream>>>(W2, W2T, Ff, Dd);
    wtrans_k<<<dim3(32, 32),  blk, 0, stream>>>(Wq, PWT + 0u * 1048576, Dd, Dd);
    wtrans_k<<<dim3(32, 32),  blk, 0, stream>>>(Wk, PWT + 1u * 1048576, Dd, Dd);
    wtrans_k<<<dim3(32, 32),  blk, 0, stream>>>(Wv, PWT + 2u * 1048576, Dd, Dd);
    wtrans_k<<<dim3(32, 32),  blk, 0, stream>>>(Wg, PWT + 3u * 1048576, Dd, Dd);
    wtrans_k<<<dim3(32, 32),  blk, 0, stream>>>(Wo, WoT, Dd, Dd);
    wtrans_k<<<dim3(64, 32),  blk, 0, stream>>>(Wa, WaT, Dd, 2 * Dd);

    // 1. projections: one N=4096 GEMM (q|k|v|g) + one N=2048 (a, raw)
    mgemm_k<0, f16><<<dim3(16, 64), gblk, 0, stream>>>(xb, Dd, PWT, P, PLD, Mrows, 4096, Dd, nullptr);
    mgemm_k<0, f16><<<dim3(8, 64),  gblk, 0, stream>>>(xb, Dd, WaT, ab, 2048, Mrows, 2048, Dd, nullptr);

    // 2. chunked scan (a-transform + k*v inline; y in-place over q cols of P)
    scan_pass1_k<<<CBD / 256, blk, 0, stream>>>(ab, P, chunk);
    scan_pass2_k<<<BD / 256, blk, 0, stream>>>(chunk, carry, stats);
    scan_pass3_k<<<CBD / 256, blk, 0, stream>>>(ab, P, carry, stats);

    // 3. groupnorm + silu(g) gate (in place on y cols of P)
    gn_gate_k<<<MD / (256 * 8), blk, 0, stream>>>(P, stats, gn_scale, gn_bias);

    // 4. output projection (A = y cols of P, lda=PLD) + ln1
    mgemm_k<0, f16><<<dim3(4, 64), gblk, 0, stream>>>(P, PLD, WoT, yo, Dd, Mrows, Dd, Dd, nullptr);
    ln_k<float, f16, f16><<<Mrows, blk, 0, stream>>>(x, yo, ln1_s, ln1_b, x1);

    // 5. MLP (h1 overlays P; h2 -> d_out fp32)
    mgemm_k<1, f16  ><<<dim3(16, 64), gblk, 0, stream>>>(x1, Dd, W1T, h1, Ff, Mrows, Ff, Dd, b1);
    mgemm_k<2, float><<<dim3(4, 64),  gblk, 0, stream>>>(h1, Ff, W2T, h2, Dd, Mrows, Dd, Ff, b2);

    // 6. final layernorm -> out (in place over h2: per-thread read-then-write)
    ln_k<f16, float, float><<<Mrows, blk, 0, stream>>>(x1, h2, ln2_s, ln2_b, out);
}